// Round 1
// baseline (6238.140 us; speedup 1.0000x reference)
//
#include <hip/hip_runtime.h>
#include <math.h>

typedef unsigned short ushort_t;
typedef __attribute__((ext_vector_type(4))) float f32x4;
typedef __attribute__((ext_vector_type(8))) short short8;

constexpr int BATCH = 8, T = 1024, C = 1024, NH = 16, HD = 64, NL = 8;
constexpr int MROWS = BATCH * T;  // 8192

__device__ __forceinline__ ushort_t f2bf(float f) {
  unsigned u = __builtin_bit_cast(unsigned, f);
  u += 0x7fffu + ((u >> 16) & 1u);
  return (ushort_t)(u >> 16);
}

__device__ __forceinline__ void gload_lds16(const ushort_t* g, ushort_t* l) {
  __builtin_amdgcn_global_load_lds(
      (const __attribute__((address_space(1))) unsigned int*)g,
      (__attribute__((address_space(3))) unsigned int*)l, 16, 0, 0);
}

// ---------------------------------------------------------------------------
// GEMM: out[M,N] = A[M,K](bf16) @ W[N,K](f32)^T + bias
// MODE 0: bf16 out.  MODE 1: exact-erf GELU then bf16 out.  MODE 2: resid(f32) += result
// Tiles: BM=128, BN=128, BK=64; 256 threads = 4 waves (2x2), each wave 64x64 out.
// LDS layout: [row][8 chunks of 8 bf16], phys chunk = logical chunk ^ (row&7).
// ---------------------------------------------------------------------------
template<int MODE>
__global__ __launch_bounds__(256, 2)
void gemm_kernel(const ushort_t* __restrict__ A, const float* __restrict__ W,
                 const float* __restrict__ bias, ushort_t* __restrict__ outb,
                 float* __restrict__ resid, int K, int N)
{
  __shared__ __align__(16) ushort_t As[128 * 64];
  __shared__ __align__(16) ushort_t Bs[128 * 64];
  const int tid = threadIdx.x;
  const int lane = tid & 63, wave = tid >> 6;
  const int wm = wave >> 1, wn = wave & 1;
  const int l15 = lane & 15, l4 = lane >> 4;
  const long bm0 = (long)blockIdx.x * 128;
  const long bn0 = (long)blockIdx.y * 128;
  const int brow = tid >> 1;   // B staging row 0..127
  const int bhalf = tid & 1;   // which 32-k half

  f32x4 acc[4][4] = {};

  for (int kt = 0; kt < K; kt += 64) {
    __syncthreads();
    // ---- stage A (bf16, global_load_lds, pre-swizzled source) ----
#pragma unroll
    for (int j = 0; j < 4; ++j) {
      int cidx = j * 256 + tid;          // 1024 chunks of 16B
      int row = cidx >> 3;
      int pc = cidx & 7;
      int cl = pc ^ (row & 7);
      const ushort_t* src = A + (size_t)(bm0 + row) * K + kt + cl * 8;
      gload_lds16(src, &As[cidx * 8]);
    }
    // ---- stage B (f32 -> bf16 reg staging, swizzled ds_write_b128) ----
    {
      const float* wsrc = W + (size_t)(bn0 + brow) * K + kt + bhalf * 32;
      f32x4 tv[8];
#pragma unroll
      for (int i = 0; i < 8; ++i) tv[i] = ((const f32x4*)wsrc)[i];
#pragma unroll
      for (int j2 = 0; j2 < 4; ++j2) {
        short8 cv;
#pragma unroll
        for (int e = 0; e < 8; ++e) {
          float f = tv[j2 * 2 + (e >> 2)][e & 3];
          cv[e] = (short)f2bf(f);
        }
        int c = bhalf * 4 + j2;
        int p = c ^ (brow & 7);
        *(short8*)&Bs[brow * 64 + p * 8] = cv;
      }
    }
    __syncthreads();
    // ---- compute: 2 k-steps x 16 mfma ----
#pragma unroll
    for (int ks = 0; ks < 2; ++ks) {
      short8 af[4], bfr[4];
#pragma unroll
      for (int mi = 0; mi < 4; ++mi) {
        int row = wm * 64 + mi * 16 + l15;
        int p = (ks * 4 + l4) ^ (row & 7);
        af[mi] = *(const short8*)&As[row * 64 + p * 8];
      }
#pragma unroll
      for (int ni = 0; ni < 4; ++ni) {
        int row = wn * 64 + ni * 16 + l15;
        int p = (ks * 4 + l4) ^ (row & 7);
        bfr[ni] = *(const short8*)&Bs[row * 64 + p * 8];
      }
#pragma unroll
      for (int mi = 0; mi < 4; ++mi)
#pragma unroll
        for (int ni = 0; ni < 4; ++ni)
          acc[mi][ni] = __builtin_amdgcn_mfma_f32_16x16x32_bf16(
              af[mi], bfr[ni], acc[mi][ni], 0, 0, 0);
    }
  }

  // ---- epilogue ----
#pragma unroll
  for (int ni = 0; ni < 4; ++ni) {
    long col = bn0 + wn * 64 + ni * 16 + l15;
    float bv = bias[col];
#pragma unroll
    for (int mi = 0; mi < 4; ++mi) {
#pragma unroll
      for (int r = 0; r < 4; ++r) {
        long row = bm0 + wm * 64 + mi * 16 + l4 * 4 + r;
        float v = acc[mi][ni][r] + bv;
        if (MODE == 1) v = 0.5f * v * (1.0f + erff(v * 0.70710678118f));
        if (MODE == 2) {
          float* rp = resid + (size_t)row * N + col;
          *rp = *rp + v;
        } else {
          outb[(size_t)row * N + col] = f2bf(v);
        }
      }
    }
  }
}

// ---------------------------------------------------------------------------
// Fused block-causal flash attention. Block = (q-tile of 64, head, batch).
// Mask == "kv 64-block index <= q 64-block index" (full blocks, no -inf).
// 4 waves; wave w owns q rows w*16..w*16+15. K/Vt shared in LDS, online softmax.
// ---------------------------------------------------------------------------
__global__ __launch_bounds__(256, 2)
void attn_kernel(const ushort_t* __restrict__ q, const ushort_t* __restrict__ k,
                 const ushort_t* __restrict__ v, ushort_t* __restrict__ y)
{
  __shared__ __align__(16) ushort_t Qs[64 * 64];
  __shared__ __align__(16) ushort_t Ks[64 * 64];
  __shared__ __align__(16) ushort_t Vts[64 * 64];  // transposed: [d][kv]
  __shared__ __align__(16) ushort_t Ps[64 * 64];
  const int tid = threadIdx.x;
  const int lane = tid & 63, wave = tid >> 6;
  const int l15 = lane & 15, l4 = lane >> 4;
  const int w16 = wave * 16;
  const int qb = blockIdx.x, h = blockIdx.y, b = blockIdx.z;
  const int coff = h * HD;
  const size_t qrow0 = (size_t)(b * T + qb * 64);

  // stage Q once
#pragma unroll
  for (int j = 0; j < 2; ++j) {
    int cidx = j * 256 + tid;
    int row = cidx >> 3, pc = cidx & 7, cl = pc ^ (row & 7);
    const ushort_t* src = q + (qrow0 + row) * C + coff + cl * 8;
    gload_lds16(src, &Qs[cidx * 8]);
  }

  f32x4 o[4] = {};
  float mrun[4] = {-INFINITY, -INFINITY, -INFINITY, -INFINITY};
  float lrun[4] = {0.f, 0.f, 0.f, 0.f};

  __syncthreads();

  for (int kvb = 0; kvb <= qb; ++kvb) {
    const size_t krow0 = (size_t)(b * T + kvb * 64);
    // stage K
#pragma unroll
    for (int j = 0; j < 2; ++j) {
      int cidx = j * 256 + tid;
      int row = cidx >> 3, pc = cidx & 7, cl = pc ^ (row & 7);
      const ushort_t* src = k + (krow0 + row) * C + coff + cl * 8;
      gload_lds16(src, &Ks[cidx * 8]);
    }
    // stage V transposed: Vts[d][kv]
#pragma unroll
    for (int pass = 0; pass < 2; ++pass) {
      int dc = (tid >> 6) + pass * 4;
      int kvr = tid & 63;
      const ushort_t* src = v + (krow0 + kvr) * C + coff + dc * 8;
      short8 vv = *(const short8*)src;
#pragma unroll
      for (int i = 0; i < 8; ++i) {
        int d = dc * 8 + i;
        Vts[d * 64 + (((kvr >> 3) ^ (d & 7)) << 3) + (kvr & 7)] = (ushort_t)vv[i];
      }
    }
    __syncthreads();

    // S = Q K^T  (wave's 16 q-rows x 64 kv)
    f32x4 s[4] = {};
#pragma unroll
    for (int ks = 0; ks < 2; ++ks) {
      int arow = w16 + l15;
      int pa = (ks * 4 + l4) ^ (arow & 7);
      short8 aq = *(const short8*)&Qs[arow * 64 + pa * 8];
#pragma unroll
      for (int n = 0; n < 4; ++n) {
        int br = n * 16 + l15;
        int pb = (ks * 4 + l4) ^ (br & 7);
        short8 bk = *(const short8*)&Ks[br * 64 + pb * 8];
        s[n] = __builtin_amdgcn_mfma_f32_16x16x32_bf16(aq, bk, s[n], 0, 0, 0);
      }
    }

    // online softmax (row reduce over 16 lanes sharing l4)
#pragma unroll
    for (int r = 0; r < 4; ++r) {
      float mx = fmaxf(fmaxf(s[0][r], s[1][r]), fmaxf(s[2][r], s[3][r]));
#pragma unroll
      for (int d = 1; d < 16; d <<= 1) mx = fmaxf(mx, __shfl_xor(mx, d, 16));
      mx *= 0.125f;  // 1/sqrt(64)
      float mnew = fmaxf(mrun[r], mx);
      float alpha = __expf(mrun[r] - mnew);
      float rowsum = 0.f;
      int qr = w16 + l4 * 4 + r;
#pragma unroll
      for (int n = 0; n < 4; ++n) {
        float pv = __expf(s[n][r] * 0.125f - mnew);
        rowsum += pv;
        int kv = n * 16 + l15;
        Ps[qr * 64 + (((kv >> 3) ^ (qr & 7)) << 3) + (kv & 7)] = f2bf(pv);
      }
#pragma unroll
      for (int d = 1; d < 16; d <<= 1) rowsum += __shfl_xor(rowsum, d, 16);
      mrun[r] = mnew;
      lrun[r] = lrun[r] * alpha + rowsum;
      o[0][r] *= alpha; o[1][r] *= alpha; o[2][r] *= alpha; o[3][r] *= alpha;
    }

    // O += P V   (A-frag from own wave's P rows; B-frag from Vts)
#pragma unroll
    for (int ks = 0; ks < 2; ++ks) {
      int arow = w16 + l15;
      int pa = (ks * 4 + l4) ^ (arow & 7);
      short8 ap = *(const short8*)&Ps[arow * 64 + pa * 8];
#pragma unroll
      for (int n = 0; n < 4; ++n) {
        int vr = n * 16 + l15;
        int pb = (ks * 4 + l4) ^ (vr & 7);
        short8 bvv = *(const short8*)&Vts[vr * 64 + pb * 8];
        o[n] = __builtin_amdgcn_mfma_f32_16x16x32_bf16(ap, bvv, o[n], 0, 0, 0);
      }
    }
    __syncthreads();
  }

  // write y (bf16)
#pragma unroll
  for (int n = 0; n < 4; ++n) {
#pragma unroll
    for (int r = 0; r < 4; ++r) {
      float val = o[n][r] / lrun[r];
      y[(qrow0 + w16 + l4 * 4 + r) * C + coff + n * 16 + l15] = f2bf(val);
    }
  }
}

// ---------------------------------------------------------------------------
// LayerNorm over C=1024. One block (256 thr) per row, 4 f32 per thread.
// OUTBF16=1 -> ushort bf16 out; 0 -> f32 out.
// ---------------------------------------------------------------------------
template<int OUTBF16>
__global__ __launch_bounds__(256, 4)
void ln_kernel(const float* __restrict__ x, const float* __restrict__ w,
               const float* __restrict__ bprm, void* __restrict__ out)
{
  const size_t row = blockIdx.x;
  const int tid = threadIdx.x;
  f32x4 xv = ((const f32x4*)(x + row * 1024))[tid];
  float s1 = xv[0] + xv[1] + xv[2] + xv[3];
  float s2 = xv[0] * xv[0] + xv[1] * xv[1] + xv[2] * xv[2] + xv[3] * xv[3];
#pragma unroll
  for (int m = 1; m < 64; m <<= 1) {
    s1 += __shfl_xor(s1, m);
    s2 += __shfl_xor(s2, m);
  }
  __shared__ float red[8];
  const int wave = tid >> 6, lane = tid & 63;
  if (lane == 0) { red[wave * 2] = s1; red[wave * 2 + 1] = s2; }
  __syncthreads();
  s1 = red[0] + red[2] + red[4] + red[6];
  s2 = red[1] + red[3] + red[5] + red[7];
  const float mean = s1 * (1.f / 1024.f);
  const float var = s2 * (1.f / 1024.f) - mean * mean;
  const float rstd = rsqrtf(var + 1e-5f);
  f32x4 wv = ((const f32x4*)w)[tid];
  f32x4 bv = ((const f32x4*)bprm)[tid];
  f32x4 ov;
#pragma unroll
  for (int c2 = 0; c2 < 4; ++c2) ov[c2] = (xv[c2] - mean) * rstd * wv[c2] + bv[c2];
  if (OUTBF16) {
    ushort4 u;
    u.x = f2bf(ov[0]); u.y = f2bf(ov[1]); u.z = f2bf(ov[2]); u.w = f2bf(ov[3]);
    ((ushort4*)out)[row * 256 + tid] = u;
  } else {
    ((f32x4*)out)[row * 256 + tid] = ov;
  }
}

// ---------------------------------------------------------------------------
extern "C" void kernel_launch(void* const* d_in, const int* in_sizes, int n_in,
                              void* d_out, int out_size, void* d_ws, size_t ws_size,
                              hipStream_t stream)
{
  const float* seq  = (const float*)d_in[0];
  // d_in[1] = mask (unused: structure exploited analytically)
  const float* Wq   = (const float*)d_in[2];  const float* bq = (const float*)d_in[3];
  const float* Wk   = (const float*)d_in[4];  const float* bk = (const float*)d_in[5];
  const float* Wv   = (const float*)d_in[6];  const float* bv = (const float*)d_in[7];
  const float* Wo   = (const float*)d_in[8];  const float* bo = (const float*)d_in[9];
  const float* ln1w = (const float*)d_in[10]; const float* ln1b = (const float*)d_in[11];
  const float* ln2w = (const float*)d_in[12]; const float* ln2b = (const float*)d_in[13];
  const float* W1   = (const float*)d_in[14]; const float* b1 = (const float*)d_in[15];
  const float* W2   = (const float*)d_in[16]; const float* b2 = (const float*)d_in[17];
  const float* lnfw = (const float*)d_in[18]; const float* lnfb = (const float*)d_in[19];

  char* ws = (char*)d_ws;
  size_t off = 0;
  float* X = (float*)(ws + off);      off += (size_t)MROWS * C * 4;   // 32MB residual stream
  ushort_t* Hb = (ushort_t*)(ws + off); off += (size_t)MROWS * C * 2; // 16MB ln out
  ushort_t* Qb = (ushort_t*)(ws + off); off += (size_t)MROWS * C * 2;
  ushort_t* Kb = (ushort_t*)(ws + off); off += (size_t)MROWS * C * 2;
  ushort_t* Vb = (ushort_t*)(ws + off); off += (size_t)MROWS * C * 2;
  ushort_t* Yb = (ushort_t*)(ws + off); off += (size_t)MROWS * C * 2;
  ushort_t* Gb = (ushort_t*)(ws + off); off += (size_t)MROWS * 4 * C * 2; // 64MB gelu out

  hipMemcpyAsync(X, seq, (size_t)MROWS * C * 4, hipMemcpyDeviceToDevice, stream);

  const dim3 blk(256);
  const dim3 gN1024(64, 8);    // M/128 x N/128 for N=1024
  const dim3 gN4096(64, 32);   // for N=4096
  const dim3 gAttn(16, NH, BATCH);

  for (int i = 0; i < NL; ++i) {
    const size_t wOff = (size_t)i * C * C;
    ln_kernel<1><<<MROWS, blk, 0, stream>>>(X, ln1w + i * C, ln1b + i * C, Hb);
    gemm_kernel<0><<<gN1024, blk, 0, stream>>>(Hb, Wq + wOff, bq + i * C, Qb, nullptr, C, C);
    gemm_kernel<0><<<gN1024, blk, 0, stream>>>(Hb, Wk + wOff, bk + i * C, Kb, nullptr, C, C);
    gemm_kernel<0><<<gN1024, blk, 0, stream>>>(Hb, Wv + wOff, bv + i * C, Vb, nullptr, C, C);
    attn_kernel<<<gAttn, blk, 0, stream>>>(Qb, Kb, Vb, Yb);
    gemm_kernel<2><<<gN1024, blk, 0, stream>>>(Yb, Wo + wOff, bo + i * C, nullptr, X, C, C);
    ln_kernel<1><<<MROWS, blk, 0, stream>>>(X, ln2w + i * C, ln2b + i * C, Hb);
    gemm_kernel<1><<<gN4096, blk, 0, stream>>>(Hb, W1 + (size_t)i * 4 * C * C, b1 + (size_t)i * 4 * C,
                                               Gb, nullptr, C, 4 * C);
    gemm_kernel<2><<<gN1024, blk, 0, stream>>>(Gb, W2 + (size_t)i * 4 * C * C, b2 + i * C,
                                               nullptr, X, 4 * C, C);
  }
  ln_kernel<0><<<MROWS, blk, 0, stream>>>(X, lnfw, lnfb, (float*)d_out);
}

// Round 2
// 3483.327 us; speedup vs baseline: 1.7909x; 1.7909x over previous
//
#include <hip/hip_runtime.h>
#include <math.h>

typedef unsigned short ushort_t;
typedef __attribute__((ext_vector_type(4))) float f32x4;
typedef __attribute__((ext_vector_type(8))) short short8;

constexpr int BATCH = 8, T = 1024, C = 1024, NH = 16, HD = 64, NL = 8;
constexpr int MROWS = BATCH * T;  // 8192
constexpr int CS = 3 * C;         // packed QKV row stride

__device__ __forceinline__ ushort_t f2bf(float f) {
  unsigned u = __builtin_bit_cast(unsigned, f);
  u += 0x7fffu + ((u >> 16) & 1u);
  return (ushort_t)(u >> 16);
}

__device__ __forceinline__ void gload_lds16(const ushort_t* g, ushort_t* l) {
  __builtin_amdgcn_global_load_lds(
      (const __attribute__((address_space(1))) unsigned int*)g,
      (__attribute__((address_space(3))) unsigned int*)l, 16, 0, 0);
}

// ---------------------------------------------------------------------------
// Per-layer weight conversion f32->bf16 + QKV packing.
// Groups of 8 elements. wqkv rows: [0,1024)=Wq, [1024,2048)=Wk, [2048,3072)=Wv.
// Block 6144 packs the QKV bias (f32, no conversion).
// ---------------------------------------------------------------------------
__global__ __launch_bounds__(256, 8)
void convw_kernel(const float* __restrict__ Wq, const float* __restrict__ Wk,
                  const float* __restrict__ Wv, const float* __restrict__ Wo,
                  const float* __restrict__ W1, const float* __restrict__ W2,
                  const float* __restrict__ bq, const float* __restrict__ bk,
                  const float* __restrict__ bv,
                  ushort_t* __restrict__ wqkv, ushort_t* __restrict__ wo,
                  ushort_t* __restrict__ w1, ushort_t* __restrict__ w2,
                  float* __restrict__ bqkv)
{
  if (blockIdx.x == 6144) {
    int t = threadIdx.x;
    if (t < 384) {
      const float* s = (t < 128) ? (bq + t * 8)
                     : (t < 256) ? (bk + (t - 128) * 8)
                                 : (bv + (t - 256) * 8);
      f32x4 a = ((const f32x4*)s)[0], b = ((const f32x4*)s)[1];
      ((f32x4*)(bqkv + t * 8))[0] = a;
      ((f32x4*)(bqkv + t * 8))[1] = b;
    }
    return;
  }
  int g = blockIdx.x * 256 + threadIdx.x;
  const float* src;
  ushort_t* dst;
  if (g < 393216) {
    int which = g >> 17;            // 131072 groups per [1024x1024] matrix
    int r = g & 131071;
    src = (which == 0 ? Wq : which == 1 ? Wk : Wv) + (size_t)r * 8;
    dst = wqkv + (size_t)g * 8;
  } else if (g < 524288) {
    int r = g - 393216;
    src = Wo + (size_t)r * 8; dst = wo + (size_t)r * 8;
  } else if (g < 1048576) {
    int r = g - 524288;
    src = W1 + (size_t)r * 8; dst = w1 + (size_t)r * 8;
  } else {
    int r = g - 1048576;
    src = W2 + (size_t)r * 8; dst = w2 + (size_t)r * 8;
  }
  f32x4 a = ((const f32x4*)src)[0], b = ((const f32x4*)src)[1];
  short8 o;
#pragma unroll
  for (int e = 0; e < 4; ++e) { o[e] = (short)f2bf(a[e]); o[e + 4] = (short)f2bf(b[e]); }
  *(short8*)dst = o;
}

// ---------------------------------------------------------------------------
// GEMM: out[M,N] = A[M,K](bf16) @ Wb[N,K](bf16)^T + bias
// MODE 0: bf16 out. MODE 1: exact-erf GELU, bf16 out. MODE 2: resid(f32) += v.
// BM=BN=128, BK=64, 256 thr = 4 waves (2x2). Double-buffered LDS, 2-phase:
// issue STAGE(t+1) -> ds_read(t)+MFMA -> one vmcnt(0)+barrier per K-step.
// LDS layout [row][8 chunks of 8 bf16], phys chunk = logical ^ (row&7);
// staged via linear-dest gload_lds with inverse-swizzled global source.
// ---------------------------------------------------------------------------
template<int MODE>
__global__ __launch_bounds__(256, 2)
void gemm_kernel(const ushort_t* __restrict__ A, const ushort_t* __restrict__ Wb,
                 const float* __restrict__ bias, ushort_t* __restrict__ outb,
                 float* __restrict__ resid, int K, int N)
{
  __shared__ __align__(16) ushort_t As[2][128 * 64];
  __shared__ __align__(16) ushort_t Bs[2][128 * 64];
  const int tid = threadIdx.x;
  const int lane = tid & 63, wave = tid >> 6;
  const int wm = wave >> 1, wn = wave & 1;
  const int l15 = lane & 15, l4 = lane >> 4;
  const long bm0 = (long)blockIdx.x * 128;
  const long bn0 = (long)blockIdx.y * 128;

  f32x4 acc[4][4] = {};

  auto stage = [&](int buf, int kt) {
#pragma unroll
    for (int j = 0; j < 4; ++j) {
      int cidx = j * 256 + tid;          // 1024 chunks of 16B each
      int row = cidx >> 3;
      int cl = (cidx & 7) ^ (row & 7);   // inverse-swizzled source column
      gload_lds16(A + (size_t)(bm0 + row) * K + kt + cl * 8, &As[buf][cidx * 8]);
      gload_lds16(Wb + (size_t)(bn0 + row) * K + kt + cl * 8, &Bs[buf][cidx * 8]);
    }
  };

  const int nt = K >> 6;
  stage(0, 0);
  __syncthreads();  // drains vmcnt(0): buf0 ready

  for (int t = 0; t < nt; ++t) {
    const int cur = t & 1;
    if (t + 1 < nt) stage(cur ^ 1, (t + 1) << 6);
#pragma unroll
    for (int ks = 0; ks < 2; ++ks) {
      short8 af[4], bfr[4];
#pragma unroll
      for (int mi = 0; mi < 4; ++mi) {
        int row = wm * 64 + mi * 16 + l15;
        int p = (ks * 4 + l4) ^ (row & 7);
        af[mi] = *(const short8*)&As[cur][row * 64 + p * 8];
      }
#pragma unroll
      for (int ni = 0; ni < 4; ++ni) {
        int row = wn * 64 + ni * 16 + l15;
        int p = (ks * 4 + l4) ^ (row & 7);
        bfr[ni] = *(const short8*)&Bs[cur][row * 64 + p * 8];
      }
#pragma unroll
      for (int mi = 0; mi < 4; ++mi)
#pragma unroll
        for (int ni = 0; ni < 4; ++ni)
          acc[mi][ni] = __builtin_amdgcn_mfma_f32_16x16x32_bf16(
              af[mi], bfr[ni], acc[mi][ni], 0, 0, 0);
    }
    __syncthreads();  // drains stage's vmcnt + all waves done reading buf[cur]
  }

  // ---- epilogue ----
#pragma unroll
  for (int ni = 0; ni < 4; ++ni) {
    long col = bn0 + wn * 64 + ni * 16 + l15;
    float bv = bias[col];
#pragma unroll
    for (int mi = 0; mi < 4; ++mi) {
#pragma unroll
      for (int r = 0; r < 4; ++r) {
        long row = bm0 + wm * 64 + mi * 16 + l4 * 4 + r;
        float v = acc[mi][ni][r] + bv;
        if (MODE == 1) v = 0.5f * v * (1.0f + erff(v * 0.70710678118f));
        if (MODE == 2) {
          float* rp = resid + (size_t)row * N + col;
          *rp = *rp + v;
        } else {
          outb[(size_t)row * N + col] = f2bf(v);
        }
      }
    }
  }
}

// ---------------------------------------------------------------------------
// Fused block-causal flash attention over packed QKV [8192][3072] bf16.
// Block = (q-tile 64, head, batch). Mask == "kv-block <= q-block" exactly.
// ---------------------------------------------------------------------------
__global__ __launch_bounds__(256, 2)
void attn_kernel(const ushort_t* __restrict__ qkv, ushort_t* __restrict__ y)
{
  __shared__ __align__(16) ushort_t Qs[64 * 64];
  __shared__ __align__(16) ushort_t Ks[64 * 64];
  __shared__ __align__(16) ushort_t Vts[64 * 64];  // transposed: [d][kv]
  __shared__ __align__(16) ushort_t Ps[64 * 64];
  const int tid = threadIdx.x;
  const int lane = tid & 63, wave = tid >> 6;
  const int l15 = lane & 15, l4 = lane >> 4;
  const int w16 = wave * 16;
  const int qb = blockIdx.x, h = blockIdx.y, b = blockIdx.z;
  const int qoff = h * HD, koff = C + h * HD, voff = 2 * C + h * HD;
  const size_t qrow0 = (size_t)(b * T + qb * 64);

  // stage Q once
#pragma unroll
  for (int j = 0; j < 2; ++j) {
    int cidx = j * 256 + tid;
    int row = cidx >> 3, cl = (cidx & 7) ^ (row & 7);
    gload_lds16(qkv + (qrow0 + row) * CS + qoff + cl * 8, &Qs[cidx * 8]);
  }

  f32x4 o[4] = {};
  float mrun[4] = {-INFINITY, -INFINITY, -INFINITY, -INFINITY};
  float lrun[4] = {0.f, 0.f, 0.f, 0.f};

  __syncthreads();

  for (int kvb = 0; kvb <= qb; ++kvb) {
    const size_t krow0 = (size_t)(b * T + kvb * 64);
    // stage K
#pragma unroll
    for (int j = 0; j < 2; ++j) {
      int cidx = j * 256 + tid;
      int row = cidx >> 3, cl = (cidx & 7) ^ (row & 7);
      gload_lds16(qkv + (krow0 + row) * CS + koff + cl * 8, &Ks[cidx * 8]);
    }
    // stage V transposed: Vts[d][kv], swizzled
#pragma unroll
    for (int pass = 0; pass < 2; ++pass) {
      int dc = (tid >> 6) + pass * 4;
      int kvr = tid & 63;
      const ushort_t* src = qkv + (krow0 + kvr) * CS + voff + dc * 8;
      short8 vv = *(const short8*)src;
#pragma unroll
      for (int i = 0; i < 8; ++i) {
        int d = dc * 8 + i;
        Vts[d * 64 + (((kvr >> 3) ^ (d & 7)) << 3) + (kvr & 7)] = (ushort_t)vv[i];
      }
    }
    __syncthreads();

    // S = Q K^T
    f32x4 s[4] = {};
#pragma unroll
    for (int ks = 0; ks < 2; ++ks) {
      int arow = w16 + l15;
      int pa = (ks * 4 + l4) ^ (arow & 7);
      short8 aq = *(const short8*)&Qs[arow * 64 + pa * 8];
#pragma unroll
      for (int n = 0; n < 4; ++n) {
        int br = n * 16 + l15;
        int pb = (ks * 4 + l4) ^ (br & 7);
        short8 bk2 = *(const short8*)&Ks[br * 64 + pb * 8];
        s[n] = __builtin_amdgcn_mfma_f32_16x16x32_bf16(aq, bk2, s[n], 0, 0, 0);
      }
    }

    // online softmax (row reduce over 16 lanes sharing l4)
#pragma unroll
    for (int r = 0; r < 4; ++r) {
      float mx = fmaxf(fmaxf(s[0][r], s[1][r]), fmaxf(s[2][r], s[3][r]));
#pragma unroll
      for (int d = 1; d < 16; d <<= 1) mx = fmaxf(mx, __shfl_xor(mx, d, 16));
      mx *= 0.125f;  // 1/sqrt(64)
      float mnew = fmaxf(mrun[r], mx);
      float alpha = __expf(mrun[r] - mnew);
      float rowsum = 0.f;
      int qr = w16 + l4 * 4 + r;
#pragma unroll
      for (int n = 0; n < 4; ++n) {
        float pv = __expf(s[n][r] * 0.125f - mnew);
        rowsum += pv;
        int kv = n * 16 + l15;
        Ps[qr * 64 + (((kv >> 3) ^ (qr & 7)) << 3) + (kv & 7)] = f2bf(pv);
      }
#pragma unroll
      for (int d = 1; d < 16; d <<= 1) rowsum += __shfl_xor(rowsum, d, 16);
      mrun[r] = mnew;
      lrun[r] = lrun[r] * alpha + rowsum;
      o[0][r] *= alpha; o[1][r] *= alpha; o[2][r] *= alpha; o[3][r] *= alpha;
    }

    // O += P V
#pragma unroll
    for (int ks = 0; ks < 2; ++ks) {
      int arow = w16 + l15;
      int pa = (ks * 4 + l4) ^ (arow & 7);
      short8 ap = *(const short8*)&Ps[arow * 64 + pa * 8];
#pragma unroll
      for (int n = 0; n < 4; ++n) {
        int vr = n * 16 + l15;
        int pb = (ks * 4 + l4) ^ (vr & 7);
        short8 bvv = *(const short8*)&Vts[vr * 64 + pb * 8];
        o[n] = __builtin_amdgcn_mfma_f32_16x16x32_bf16(ap, bvv, o[n], 0, 0, 0);
      }
    }
    __syncthreads();
  }

  // write y (bf16, stride C)
#pragma unroll
  for (int n = 0; n < 4; ++n) {
#pragma unroll
    for (int r = 0; r < 4; ++r) {
      float val = o[n][r] / lrun[r];
      y[(qrow0 + w16 + l4 * 4 + r) * C + h * HD + n * 16 + l15] = f2bf(val);
    }
  }
}

// ---------------------------------------------------------------------------
// LayerNorm over C=1024. One block (256 thr) per row.
// ---------------------------------------------------------------------------
template<int OUTBF16>
__global__ __launch_bounds__(256, 4)
void ln_kernel(const float* __restrict__ x, const float* __restrict__ w,
               const float* __restrict__ bprm, void* __restrict__ out)
{
  const size_t row = blockIdx.x;
  const int tid = threadIdx.x;
  f32x4 xv = ((const f32x4*)(x + row * 1024))[tid];
  float s1 = xv[0] + xv[1] + xv[2] + xv[3];
  float s2 = xv[0] * xv[0] + xv[1] * xv[1] + xv[2] * xv[2] + xv[3] * xv[3];
#pragma unroll
  for (int m = 1; m < 64; m <<= 1) {
    s1 += __shfl_xor(s1, m);
    s2 += __shfl_xor(s2, m);
  }
  __shared__ float red[8];
  const int wave = tid >> 6, lane = tid & 63;
  if (lane == 0) { red[wave * 2] = s1; red[wave * 2 + 1] = s2; }
  __syncthreads();
  s1 = red[0] + red[2] + red[4] + red[6];
  s2 = red[1] + red[3] + red[5] + red[7];
  const float mean = s1 * (1.f / 1024.f);
  const float var = s2 * (1.f / 1024.f) - mean * mean;
  const float rstd = rsqrtf(var + 1e-5f);
  f32x4 wv = ((const f32x4*)w)[tid];
  f32x4 bv = ((const f32x4*)bprm)[tid];
  f32x4 ov;
#pragma unroll
  for (int c2 = 0; c2 < 4; ++c2) ov[c2] = (xv[c2] - mean) * rstd * wv[c2] + bv[c2];
  if (OUTBF16) {
    ushort4 u;
    u.x = f2bf(ov[0]); u.y = f2bf(ov[1]); u.z = f2bf(ov[2]); u.w = f2bf(ov[3]);
    ((ushort4*)out)[row * 256 + tid] = u;
  } else {
    ((f32x4*)out)[row * 256 + tid] = ov;
  }
}

// ---------------------------------------------------------------------------
extern "C" void kernel_launch(void* const* d_in, const int* in_sizes, int n_in,
                              void* d_out, int out_size, void* d_ws, size_t ws_size,
                              hipStream_t stream)
{
  const float* seq  = (const float*)d_in[0];
  const float* Wq   = (const float*)d_in[2];  const float* bq = (const float*)d_in[3];
  const float* Wk   = (const float*)d_in[4];  const float* bk = (const float*)d_in[5];
  const float* Wv   = (const float*)d_in[6];  const float* bv = (const float*)d_in[7];
  const float* Wo   = (const float*)d_in[8];  const float* bo = (const float*)d_in[9];
  const float* ln1w = (const float*)d_in[10]; const float* ln1b = (const float*)d_in[11];
  const float* ln2w = (const float*)d_in[12]; const float* ln2b = (const float*)d_in[13];
  const float* W1   = (const float*)d_in[14]; const float* b1 = (const float*)d_in[15];
  const float* W2   = (const float*)d_in[16]; const float* b2 = (const float*)d_in[17];
  const float* lnfw = (const float*)d_in[18]; const float* lnfb = (const float*)d_in[19];

  char* ws = (char*)d_ws;
  size_t off = 0;
  float* X = (float*)(ws + off);         off += (size_t)MROWS * C * 4;       // 32MB residual
  ushort_t* Hb = (ushort_t*)(ws + off);  off += (size_t)MROWS * C * 2;       // 16MB ln out
  ushort_t* Yb = (ushort_t*)(ws + off);  off += (size_t)MROWS * C * 2;       // 16MB attn out
  ushort_t* BIG = (ushort_t*)(ws + off); off += (size_t)MROWS * 4 * C * 2;   // 64MB QKV|gelu
  ushort_t* wqkv = (ushort_t*)(ws + off); off += (size_t)3 * C * C * 2;      // 6MB
  ushort_t* wo   = (ushort_t*)(ws + off); off += (size_t)C * C * 2;          // 2MB
  ushort_t* w1   = (ushort_t*)(ws + off); off += (size_t)4 * C * C * 2;      // 8MB
  ushort_t* w2   = (ushort_t*)(ws + off); off += (size_t)4 * C * C * 2;      // 8MB
  float* bqkv = (float*)(ws + off);       off += (size_t)3 * C * 4;          // 12KB
  ushort_t* QKVb = BIG;   // [8192][3072], live qkv-gemm -> attn
  ushort_t* Gb = BIG;     // [8192][4096], live w1 -> w2

  hipMemcpyAsync(X, seq, (size_t)MROWS * C * 4, hipMemcpyDeviceToDevice, stream);

  const dim3 blk(256);
  const dim3 gQKV(64, 24);     // N=3072
  const dim3 gN1024(64, 8);    // N=1024
  const dim3 gN4096(64, 32);   // N=4096
  const dim3 gAttn(16, NH, BATCH);
  const dim3 gConv(6145);

  for (int i = 0; i < NL; ++i) {
    const size_t w1Off = (size_t)i * C * C;
    const size_t w4Off = (size_t)i * 4 * C * C;
    convw_kernel<<<gConv, blk, 0, stream>>>(Wq + w1Off, Wk + w1Off, Wv + w1Off,
                                            Wo + w1Off, W1 + w4Off, W2 + w4Off,
                                            bq + i * C, bk + i * C, bv + i * C,
                                            wqkv, wo, w1, w2, bqkv);
    ln_kernel<1><<<MROWS, blk, 0, stream>>>(X, ln1w + i * C, ln1b + i * C, Hb);
    gemm_kernel<0><<<gQKV, blk, 0, stream>>>(Hb, wqkv, bqkv, QKVb, nullptr, C, CS);
    attn_kernel<<<gAttn, blk, 0, stream>>>(QKVb, Yb);
    gemm_kernel<2><<<gN1024, blk, 0, stream>>>(Yb, wo, bo + i * C, nullptr, X, C, C);
    ln_kernel<1><<<MROWS, blk, 0, stream>>>(X, ln2w + i * C, ln2b + i * C, Hb);
    gemm_kernel<1><<<gN4096, blk, 0, stream>>>(Hb, w1, b1 + (size_t)i * 4 * C, Gb, nullptr, C, 4 * C);
    gemm_kernel<2><<<gN1024, blk, 0, stream>>>(Gb, w2, b2 + i * C, nullptr, X, 4 * C, C);
  }
  ln_kernel<0><<<MROWS, blk, 0, stream>>>(X, lnfw, lnfb, (float*)d_out);
}